// Round 1
// baseline (644.916 us; speedup 1.0000x reference)
//
#include <hip/hip_runtime.h>

// GCN 2-layer: out = Ahat * relu(Ahat*(x@W1)+b1) @ W2 ... + b2
// Ahat = D^-1/2 (A+I) D^-1/2, deg from dst (incl self-loop).
//
// Pipeline (all on `stream`):
//  memset cnt,cur=0 -> count -> scan(3 kernels incl fused dinv) -> fill CSR
//  -> prep W1t/W2t (bf16, transposed) -> GEMM1 (f32 x -> bf16 g1=dinv*x@W1)
//  -> agg1 (CSR gather, relu, +b1 -> bf16 z1) -> GEMM2 (g2=dinv*z1@W2)
//  -> agg2 (CSR gather, +b2 -> f32 out)

typedef float   f32x4  __attribute__((ext_vector_type(4)));
typedef float   f32x2  __attribute__((ext_vector_type(2)));
typedef __bf16  bf16x8 __attribute__((ext_vector_type(8)));
typedef __bf16  bf16x4 __attribute__((ext_vector_type(4)));
typedef __bf16  bf16x2 __attribute__((ext_vector_type(2)));

#define NN 100000
#define EE 800000
#define FIN 512
#define HID 256
#define DOUT 128

// ---------------- CSR build ----------------
__global__ void k_count(const int* __restrict__ dst, int E, int* __restrict__ cnt) {
    int e = blockIdx.x * 256 + threadIdx.x;
    if (e < E) atomicAdd(&cnt[dst[e]], 1);
}

// per-block exclusive scan (1024/block), block sums out
__global__ void k_scan1(const int* __restrict__ cnt, int* __restrict__ off,
                        int* __restrict__ sums, int n) {
    __shared__ int s[1024];
    int i = blockIdx.x * 1024 + threadIdx.x;
    int v = (i < n) ? cnt[i] : 0;
    s[threadIdx.x] = v;
    __syncthreads();
    for (int d = 1; d < 1024; d <<= 1) {
        int t = (threadIdx.x >= d) ? s[threadIdx.x - d] : 0;
        __syncthreads();
        s[threadIdx.x] += t;
        __syncthreads();
    }
    if (i < n) off[i] = s[threadIdx.x] - v;       // exclusive within block
    if (threadIdx.x == 1023) sums[blockIdx.x] = s[1023];
}

__global__ void k_scan2(int* __restrict__ sums, int nb) {
    __shared__ int s[128];
    int t = threadIdx.x;
    int v = (t < nb) ? sums[t] : 0;
    s[t] = v;
    __syncthreads();
    for (int d = 1; d < 128; d <<= 1) {
        int u = (t >= d) ? s[t - d] : 0;
        __syncthreads();
        s[t] += u;
        __syncthreads();
    }
    if (t < nb) sums[t] = s[t] - v;               // exclusive block base
}

__global__ void k_scan_fix(int* __restrict__ off, const int* __restrict__ sums,
                           const int* __restrict__ cnt, float* __restrict__ dinv, int n) {
    int i = blockIdx.x * 256 + threadIdx.x;
    if (i < n) {
        off[i] += sums[i >> 10];
        dinv[i] = rsqrtf((float)(cnt[i] + 1));    // +1 self loop
    }
}

__global__ void k_fill(const int* __restrict__ src, const int* __restrict__ dst, int E,
                       const int* __restrict__ off, int* __restrict__ cur,
                       int* __restrict__ csr) {
    int e = blockIdx.x * 256 + threadIdx.x;
    if (e < E) {
        int d = dst[e];
        int p = atomicAdd(&cur[d], 1);
        csr[off[d] + p] = src[e];
    }
}

// ---------------- weight prep: f32 [K][N] -> bf16 transposed [N][K] ----------------
__global__ void k_prep_w(const float* __restrict__ W1, const float* __restrict__ W2,
                         __bf16* __restrict__ W1t, __bf16* __restrict__ W2t) {
    int id = blockIdx.x * 256 + threadIdx.x;
    if (id < FIN * HID) {
        int k = id >> 8, n = id & 255;            // W1 [512][256]
        W1t[n * FIN + k] = (__bf16)W1[id];
    }
    int id2 = id - FIN * HID;
    if (id2 >= 0 && id2 < HID * DOUT) {
        int k = id2 >> 7, n = id2 & 127;          // W2 [256][128]
        W2t[n * HID + k] = (__bf16)W2[id2];
    }
}

// ---------------- GEMM: out[rg][c] = bf16( dinv[rg] * sum_k A[rg][k]*B[k][c] ) ----------------
// BM=128, BK=32, BN = WAVES_N*64, threads = 128*WAVES_N. 2 waves in M, WAVES_N in N.
// A source is f32 (AF32, converted during staging) or bf16. B pre-transposed bf16 [BN][K].
template <int WAVES_N, bool AF32, int KTOT>
__global__ __launch_bounds__(128 * WAVES_N) void k_gemm(
    const void* __restrict__ Asrc, const __bf16* __restrict__ Bt,
    const float* __restrict__ dinv, __bf16* __restrict__ out, int M) {
    constexpr int BN  = WAVES_N * 64;
    constexpr int LDA = 40;                       // padded row stride (bf16) -> 80B, conflict-free
    __shared__ __bf16 A_lds[128 * LDA];
    __shared__ __bf16 B_lds[BN * LDA];

    const int tid = threadIdx.x;
    const int l = tid & 63, wid = tid >> 6;
    const int wm = wid & 1, wn = wid >> 1;
    const int bm = blockIdx.x;
    const int r15 = l & 15, hi = l >> 4;

    f32x4 acc[4][4] = {};

    for (int kb = 0; kb < KTOT / 32; ++kb) {
        __syncthreads();
        // ---- stage A tile (128 x 32) ----
        if constexpr (AF32) {                     // 512 threads: 8 f32 each
            int row = tid >> 2, seg = tid & 3;
            long rg = (long)bm * 128 + row;
            if (rg >= M) rg = M - 1;
            const float* ap = (const float*)Asrc + rg * (long)KTOT + kb * 32 + seg * 8;
            f32x4 x0 = *(const f32x4*)ap;
            f32x4 x1 = *(const f32x4*)(ap + 4);
            bf16x8 w;
            w[0] = (__bf16)x0[0]; w[1] = (__bf16)x0[1]; w[2] = (__bf16)x0[2]; w[3] = (__bf16)x0[3];
            w[4] = (__bf16)x1[0]; w[5] = (__bf16)x1[1]; w[6] = (__bf16)x1[2]; w[7] = (__bf16)x1[3];
            *(bf16x8*)&A_lds[row * LDA + seg * 8] = w;
        } else {                                  // 256 threads: 16 bf16 each
            int row = tid >> 1, seg = tid & 1;
            long rg = (long)bm * 128 + row;
            if (rg >= M) rg = M - 1;
            const __bf16* ap = (const __bf16*)Asrc + rg * (long)KTOT + kb * 32 + seg * 16;
            bf16x8 u0 = *(const bf16x8*)ap;
            bf16x8 u1 = *(const bf16x8*)(ap + 8);
            *(bf16x8*)&A_lds[row * LDA + seg * 16]     = u0;
            *(bf16x8*)&A_lds[row * LDA + seg * 16 + 8] = u1;
        }
        // ---- stage B tile (BN x 32), source [BN][KTOT] bf16 ----
        {
            int n = tid >> 1, seg = tid & 1;      // covers BN rows in both configs
            const __bf16* bp = Bt + (long)n * KTOT + kb * 32 + seg * 16;
            bf16x8 u0 = *(const bf16x8*)bp;
            bf16x8 u1 = *(const bf16x8*)(bp + 8);
            *(bf16x8*)&B_lds[n * LDA + seg * 16]     = u0;
            *(bf16x8*)&B_lds[n * LDA + seg * 16 + 8] = u1;
        }
        __syncthreads();

        bf16x8 af[4], bfr[4];
#pragma unroll
        for (int m = 0; m < 4; m++)
            af[m] = *(const bf16x8*)&A_lds[(wm * 64 + m * 16 + r15) * LDA + hi * 8];
#pragma unroll
        for (int n = 0; n < 4; n++)
            bfr[n] = *(const bf16x8*)&B_lds[(wn * 64 + n * 16 + r15) * LDA + hi * 8];
#pragma unroll
        for (int m = 0; m < 4; m++)
#pragma unroll
            for (int n = 0; n < 4; n++)
                // swapped operands: D row-index <- N dim, col-index <- M dim,
                // so each lane's 4 regs are 4 consecutive COLUMNS of one row.
                acc[m][n] = __builtin_amdgcn_mfma_f32_16x16x32_bf16(bfr[n], af[m], acc[m][n], 0, 0, 0);
    }

    // epilogue: g = bf16(dinv[row] * acc), packed 4-col stores
#pragma unroll
    for (int m = 0; m < 4; m++) {
        long rg = (long)bm * 128 + wm * 64 + m * 16 + r15;
        if (rg >= M) continue;
        float di = dinv[rg];
#pragma unroll
        for (int n = 0; n < 4; n++) {
            bf16x4 o;
            o[0] = (__bf16)(acc[m][n][0] * di);
            o[1] = (__bf16)(acc[m][n][1] * di);
            o[2] = (__bf16)(acc[m][n][2] * di);
            o[3] = (__bf16)(acc[m][n][3] * di);
            int c = wn * 64 + n * 16 + hi * 4;
            *(bf16x4*)(out + rg * (long)BN + c) = o;
        }
    }
}

// ---------------- aggregation 1: z1 = relu(dinv_i*(g1_i + sum g1_src) + b1), 256 feats ----------------
__global__ void k_agg1(const __bf16* __restrict__ g1, const int* __restrict__ csr,
                       const int* __restrict__ off, const int* __restrict__ cnt,
                       const float* __restrict__ dinv, const float* __restrict__ b1,
                       __bf16* __restrict__ z1, int n) {
    int node = blockIdx.x * 4 + (threadIdx.x >> 6);
    if (node >= n) return;
    int l = threadIdx.x & 63;                     // lane handles feats 4l..4l+3
    bf16x4 v = *(const bf16x4*)(g1 + (size_t)node * HID + l * 4);
    float a0 = (float)v[0], a1 = (float)v[1], a2 = (float)v[2], a3 = (float)v[3];
    int s0 = off[node], e0 = s0 + cnt[node];
    for (int e = s0; e < e0; ++e) {
        int s = csr[e];
        bf16x4 u = *(const bf16x4*)(g1 + (size_t)s * HID + l * 4);
        a0 += (float)u[0]; a1 += (float)u[1]; a2 += (float)u[2]; a3 += (float)u[3];
    }
    float di = dinv[node];
    f32x4 b = *(const f32x4*)(b1 + l * 4);
    bf16x4 o;
    o[0] = (__bf16)fmaxf(a0 * di + b[0], 0.f);
    o[1] = (__bf16)fmaxf(a1 * di + b[1], 0.f);
    o[2] = (__bf16)fmaxf(a2 * di + b[2], 0.f);
    o[3] = (__bf16)fmaxf(a3 * di + b[3], 0.f);
    *(bf16x4*)(z1 + (size_t)node * HID + l * 4) = o;
}

// ---------------- aggregation 2: out = dinv_i*(g2_i + sum g2_src) + b2, 128 feats, f32 out ----------------
__global__ void k_agg2(const __bf16* __restrict__ g2, const int* __restrict__ csr,
                       const int* __restrict__ off, const int* __restrict__ cnt,
                       const float* __restrict__ dinv, const float* __restrict__ b2,
                       float* __restrict__ out, int n) {
    int node = blockIdx.x * 4 + (threadIdx.x >> 6);
    if (node >= n) return;
    int l = threadIdx.x & 63;                     // lane handles feats 2l, 2l+1
    bf16x2 v = *(const bf16x2*)(g2 + (size_t)node * DOUT + l * 2);
    float a0 = (float)v[0], a1 = (float)v[1];
    int s0 = off[node], e0 = s0 + cnt[node];
    for (int e = s0; e < e0; ++e) {
        int s = csr[e];
        bf16x2 u = *(const bf16x2*)(g2 + (size_t)s * DOUT + l * 2);
        a0 += (float)u[0]; a1 += (float)u[1];
    }
    float di = dinv[node];
    f32x2 b = *(const f32x2*)(b2 + l * 2);
    f32x2 o;
    o[0] = a0 * di + b[0];
    o[1] = a1 * di + b[1];
    *(f32x2*)(out + (size_t)node * DOUT + l * 2) = o;
}

extern "C" void kernel_launch(void* const* d_in, const int* in_sizes, int n_in,
                              void* d_out, int out_size, void* d_ws, size_t ws_size,
                              hipStream_t stream) {
    const float* x  = (const float*)d_in[0];
    const int*   ei = (const int*)d_in[1];
    const float* W1 = (const float*)d_in[2];
    const float* b1 = (const float*)d_in[3];
    const float* W2 = (const float*)d_in[4];
    const float* b2 = (const float*)d_in[5];
    float* out = (float*)d_out;

    const int N = in_sizes[0] / FIN;   // 100000
    const int E = in_sizes[1] / 2;     // 800000
    const int* srcA = ei;
    const int* dstA = ei + E;

    // ---- workspace carve (aligned chunks) ----
    uint8_t* w = (uint8_t*)d_ws;
    auto take = [&](size_t bytes) { uint8_t* p = w; w += (bytes + 255) & ~(size_t)255; return p; };
    int*    cnt  = (int*)take((size_t)N * 4);
    int*    cur  = (int*)take((size_t)N * 4);     // cnt,cur adjacent-ish; zero separately
    int*    off  = (int*)take((size_t)N * 4);
    float*  dinv = (float*)take((size_t)N * 4);
    int*    sums = (int*)take(4096);
    int*    csr  = (int*)take((size_t)E * 4);
    __bf16* W1t  = (__bf16*)take((size_t)FIN * HID * 2);
    __bf16* W2t  = (__bf16*)take((size_t)HID * DOUT * 2);
    __bf16* g1   = (__bf16*)take((size_t)N * HID * 2);
    __bf16* z1   = (__bf16*)take((size_t)N * HID * 2);
    __bf16* g2   = (__bf16*)take((size_t)N * DOUT * 2);

    // ---- CSR build ----
    hipMemsetAsync(cnt, 0, (size_t)N * 4, stream);
    hipMemsetAsync(cur, 0, (size_t)N * 4, stream);
    k_count<<<(E + 255) / 256, 256, 0, stream>>>(dstA, E, cnt);
    int nb = (N + 1023) / 1024;                   // 98
    k_scan1<<<nb, 1024, 0, stream>>>(cnt, off, sums, N);
    k_scan2<<<1, 128, 0, stream>>>(sums, nb);
    k_scan_fix<<<(N + 255) / 256, 256, 0, stream>>>(off, sums, cnt, dinv, N);
    k_fill<<<(E + 255) / 256, 256, 0, stream>>>(srcA, dstA, E, off, cur, csr);

    // ---- weights ----
    k_prep_w<<<(FIN * HID + HID * DOUT + 255) / 256, 256, 0, stream>>>(W1, W2, W1t, W2t);

    const int gm = (N + 127) / 128;               // 782

    // ---- layer 1 ----
    k_gemm<4, true, FIN><<<gm, 512, 0, stream>>>(x, W1t, dinv, g1, N);
    k_agg1<<<(N + 3) / 4, 256, 0, stream>>>(g1, csr, off, cnt, dinv, b1, z1, N);

    // ---- layer 2 ----
    k_gemm<2, false, HID><<<gm, 256, 0, stream>>>(z1, W2t, dinv, g2, N);
    k_agg2<<<(N + 3) / 4, 256, 0, stream>>>(g2, csr, off, cnt, dinv, b2, out, N);
}

// Round 3
// 564.937 us; speedup vs baseline: 1.1416x; 1.1416x over previous
//
#include <hip/hip_runtime.h>

// GCN 2-layer: out = Ahat * relu(Ahat*(x@W1)+b1) @ W2 + b2
// Ahat = D^-1/2 (A+I) D^-1/2.
// R1 (resubmitted R2 after broker timeout): pipelined single-barrier GEMMs
// (global_load_lds for bf16 operands, reg-staged f32->bf16 for x),
// unrolled CSR gather aggs.

typedef float   f32x4  __attribute__((ext_vector_type(4)));
typedef float   f32x2  __attribute__((ext_vector_type(2)));
typedef __bf16  bf16x8 __attribute__((ext_vector_type(8)));
typedef __bf16  bf16x4 __attribute__((ext_vector_type(4)));
typedef __bf16  bf16x2 __attribute__((ext_vector_type(2)));

#define FIN 512
#define HID 256
#define DOUT 128

__device__ __forceinline__ void gload16(const void* g, void* l) {
    __builtin_amdgcn_global_load_lds((const __attribute__((address_space(1))) void*)g,
                                     (__attribute__((address_space(3))) void*)l, 16, 0, 0);
}

// ---------------- CSR build ----------------
__global__ void k_count(const int* __restrict__ dst, int E, int* __restrict__ cnt) {
    int e = blockIdx.x * 256 + threadIdx.x;
    if (e < E) atomicAdd(&cnt[dst[e]], 1);
}

__global__ void k_scan1(const int* __restrict__ cnt, int* __restrict__ off,
                        int* __restrict__ sums, int n) {
    __shared__ int s[1024];
    int i = blockIdx.x * 1024 + threadIdx.x;
    int v = (i < n) ? cnt[i] : 0;
    s[threadIdx.x] = v;
    __syncthreads();
    for (int d = 1; d < 1024; d <<= 1) {
        int t = (threadIdx.x >= d) ? s[threadIdx.x - d] : 0;
        __syncthreads();
        s[threadIdx.x] += t;
        __syncthreads();
    }
    if (i < n) off[i] = s[threadIdx.x] - v;
    if (threadIdx.x == 1023) sums[blockIdx.x] = s[1023];
}

__global__ void k_scan2(int* __restrict__ sums, int nb) {
    __shared__ int s[128];
    int t = threadIdx.x;
    int v = (t < nb) ? sums[t] : 0;
    s[t] = v;
    __syncthreads();
    for (int d = 1; d < 128; d <<= 1) {
        int u = (t >= d) ? s[t - d] : 0;
        __syncthreads();
        s[t] += u;
        __syncthreads();
    }
    if (t < nb) sums[t] = s[t] - v;
}

__global__ void k_scan_fix(int* __restrict__ off, const int* __restrict__ sums,
                           const int* __restrict__ cnt, float* __restrict__ dinv, int n) {
    int i = blockIdx.x * 256 + threadIdx.x;
    if (i < n) {
        off[i] += sums[i >> 10];
        dinv[i] = rsqrtf((float)(cnt[i] + 1));
    }
}

__global__ void k_fill(const int* __restrict__ src, const int* __restrict__ dst, int E,
                       const int* __restrict__ off, int* __restrict__ cur,
                       int* __restrict__ csr) {
    int e = blockIdx.x * 256 + threadIdx.x;
    if (e < E) {
        int d = dst[e];
        int p = atomicAdd(&cur[d], 1);
        csr[off[d] + p] = src[e];
    }
}

// ---------------- weight prep: f32 [K][N] -> bf16 transposed [N][K] ----------------
__global__ void k_prep_w(const float* __restrict__ W1, const float* __restrict__ W2,
                         __bf16* __restrict__ W1t, __bf16* __restrict__ W2t) {
    int id = blockIdx.x * 256 + threadIdx.x;
    if (id < FIN * HID) {
        int k = id >> 8, n = id & 255;
        W1t[n * FIN + k] = (__bf16)W1[id];
    }
    int id2 = id - FIN * HID;
    if (id2 >= 0 && id2 < HID * DOUT) {
        int k = id2 >> 7, n = id2 & 127;
        W2t[n * HID + k] = (__bf16)W2[id2];
    }
}

// ---------------- GEMM1: g1 = bf16(dinv * (x @ W1)), x f32 [M][512], out [M][256] ----------------
// 128x256 tile, BK=32, 256 threads (4 waves, each 64Mx128N). Single barrier/K-step.
// B via global_load_lds (linear [256][32] bf16), A reg-staged f32->bf16 ([128][32] bf16).
__global__ __launch_bounds__(256, 2) void k_gemm1(
    const float* __restrict__ x, const __bf16* __restrict__ Bt,
    const float* __restrict__ dinv, __bf16* __restrict__ g1, int M) {
    __shared__ __bf16 Albuf[2][128 * 32];
    __shared__ __bf16 Blbuf[2][256 * 32];

    const int tid = threadIdx.x;
    const int l = tid & 63, wid = tid >> 6;
    const int wm = wid & 1, wn = wid >> 1;       // wn in 0..1, covers 128 cols each
    const int r15 = l & 15, hi = l >> 4;
    const long bm = blockIdx.x;

    // A staging: thread owns row=tid>>1 (0..127), seg=tid&1 (16 f32 = 64B)
    const int arow = tid >> 1, aseg = tid & 1;
    long ag = bm * 128 + arow;
    if (ag >= M) ag = M - 1;
    const float* aptr = x + ag * (long)FIN + aseg * 16;
    const int aoff = arow * 32 + aseg * 16;      // bf16 elems into Albuf

    // B staging: 4 gload16 per wave per K-step (16KB tile)
    const int bo0 = wid * 4096;                  // wave-uniform byte base (per i: +1024)

    f32x4 acc[4][8] = {};

    auto stageB = [&](int kb, int buf) {
#pragma unroll
        for (int i = 0; i < 4; ++i) {
            int ob = bo0 + i * 1024;
            int o = ob + l * 16;
            int n = o >> 6, cb = o & 63;
            const char* src = (const char*)Bt + (long)n * (FIN * 2) + kb * 64 + cb;
            gload16(src, (char*)&Blbuf[buf][0] + ob);
        }
    };

    // ---- prologue: stage tile 0 ----
    stageB(0, 0);
    {
        const f32x4* p = (const f32x4*)aptr;
        f32x4 p0 = p[0], p1 = p[1], p2 = p[2], p3 = p[3];
        bf16x8 w0, w1;
#pragma unroll
        for (int j = 0; j < 4; ++j) {
            w0[j] = (__bf16)p0[j]; w0[j + 4] = (__bf16)p1[j];
            w1[j] = (__bf16)p2[j]; w1[j + 4] = (__bf16)p3[j];
        }
        *(bf16x8*)&Albuf[0][aoff] = w0;
        *(bf16x8*)&Albuf[0][aoff + 8] = w1;
    }
    __syncthreads();

    int cur = 0;
    constexpr int NT = FIN / 32;                 // 16
    for (int kb = 0; kb < NT; ++kb) {
        const int nxt = cur ^ 1;
        const bool pf = (kb + 1 < NT);
        f32x4 p0, p1, p2, p3;
        if (pf) {
            stageB(kb + 1, nxt);                 // async into LDS[nxt]
            const f32x4* p = (const f32x4*)(aptr + (kb + 1) * 32);
            p0 = p[0]; p1 = p[1]; p2 = p[2]; p3 = p[3];
        }

        bf16x8 af[4], bfr[8];
#pragma unroll
        for (int m = 0; m < 4; ++m)
            af[m] = *(const bf16x8*)&Albuf[cur][(wm * 64 + m * 16 + r15) * 32 + hi * 8];
#pragma unroll
        for (int n = 0; n < 8; ++n)
            bfr[n] = *(const bf16x8*)&Blbuf[cur][(wn * 128 + n * 16 + r15) * 32 + hi * 8];
#pragma unroll
        for (int m = 0; m < 4; ++m)
#pragma unroll
            for (int n = 0; n < 8; ++n)
                acc[m][n] = __builtin_amdgcn_mfma_f32_16x16x32_bf16(bfr[n], af[m], acc[m][n], 0, 0, 0);

        if (pf) {                                // cvt + LDS write after compute
            bf16x8 w0, w1;
#pragma unroll
            for (int j = 0; j < 4; ++j) {
                w0[j] = (__bf16)p0[j]; w0[j + 4] = (__bf16)p1[j];
                w1[j] = (__bf16)p2[j]; w1[j + 4] = (__bf16)p3[j];
            }
            *(bf16x8*)&Albuf[nxt][aoff] = w0;
            *(bf16x8*)&Albuf[nxt][aoff + 8] = w1;
        }
        __syncthreads();                         // drains vmcnt (gload) + lgkm
        cur = nxt;
    }

    // ---- epilogue ----
#pragma unroll
    for (int m = 0; m < 4; ++m) {
        long rg = bm * 128 + wm * 64 + m * 16 + r15;
        if (rg >= M) continue;
        float di = dinv[rg];
#pragma unroll
        for (int n = 0; n < 8; ++n) {
            bf16x4 o;
            o[0] = (__bf16)(acc[m][n][0] * di);
            o[1] = (__bf16)(acc[m][n][1] * di);
            o[2] = (__bf16)(acc[m][n][2] * di);
            o[3] = (__bf16)(acc[m][n][3] * di);
            int c = wn * 128 + n * 16 + hi * 4;
            *(bf16x4*)(g1 + rg * (long)HID + c) = o;
        }
    }
}

// ---------------- GEMM2: g2 = bf16(dinv * (z1 @ W2)), z1 bf16 [M][256], out [M][128] ----------------
// 128x128 tile, BK=32, 256 threads (4 waves, each 64x64). Both operands via global_load_lds.
__global__ __launch_bounds__(256, 3) void k_gemm2(
    const __bf16* __restrict__ z1, const __bf16* __restrict__ Bt,
    const float* __restrict__ dinv, __bf16* __restrict__ g2, int M) {
    __shared__ __bf16 Albuf[2][128 * 32];
    __shared__ __bf16 Blbuf[2][128 * 32];

    const int tid = threadIdx.x;
    const int l = tid & 63, wid = tid >> 6;
    const int wm = wid & 1, wn = wid >> 1;
    const int r15 = l & 15, hi = l >> 4;
    const long bm = blockIdx.x;

    f32x4 acc[4][4] = {};

    auto stage = [&](int kb, int buf) {
#pragma unroll
        for (int i = 0; i < 2; ++i) {            // A: 8KB = 8 instrs / 4 waves
            int ob = wid * 2048 + i * 1024;
            int o = ob + l * 16;
            long r = bm * 128 + (o >> 6);
            if (r >= M) r = M - 1;
            const char* src = (const char*)z1 + r * (HID * 2) + kb * 64 + (o & 63);
            gload16(src, (char*)&Albuf[buf][0] + ob);
        }
#pragma unroll
        for (int i = 0; i < 2; ++i) {            // B: 8KB
            int ob = wid * 2048 + i * 1024;
            int o = ob + l * 16;
            int n = o >> 6;
            const char* src = (const char*)Bt + (long)n * (HID * 2) + kb * 64 + (o & 63);
            gload16(src, (char*)&Blbuf[buf][0] + ob);
        }
    };

    stage(0, 0);
    __syncthreads();

    int cur = 0;
    constexpr int NT = HID / 32;                 // 8
    for (int kb = 0; kb < NT; ++kb) {
        const int nxt = cur ^ 1;
        if (kb + 1 < NT) stage(kb + 1, nxt);

        bf16x8 af[4], bfr[4];
#pragma unroll
        for (int m = 0; m < 4; ++m)
            af[m] = *(const bf16x8*)&Albuf[cur][(wm * 64 + m * 16 + r15) * 32 + hi * 8];
#pragma unroll
        for (int n = 0; n < 4; ++n)
            bfr[n] = *(const bf16x8*)&Blbuf[cur][(wn * 64 + n * 16 + r15) * 32 + hi * 8];
#pragma unroll
        for (int m = 0; m < 4; ++m)
#pragma unroll
            for (int n = 0; n < 4; ++n)
                acc[m][n] = __builtin_amdgcn_mfma_f32_16x16x32_bf16(bfr[n], af[m], acc[m][n], 0, 0, 0);

        __syncthreads();
        cur = nxt;
    }

#pragma unroll
    for (int m = 0; m < 4; ++m) {
        long rg = bm * 128 + wm * 64 + m * 16 + r15;
        if (rg >= M) continue;
        float di = dinv[rg];
#pragma unroll
        for (int n = 0; n < 4; ++n) {
            bf16x4 o;
            o[0] = (__bf16)(acc[m][n][0] * di);
            o[1] = (__bf16)(acc[m][n][1] * di);
            o[2] = (__bf16)(acc[m][n][2] * di);
            o[3] = (__bf16)(acc[m][n][3] * di);
            int c = wn * 64 + n * 16 + hi * 4;
            *(bf16x4*)(g2 + rg * (long)DOUT + c) = o;
        }
    }
}

// ---------------- aggregation 1: z1 = relu(dinv_i*(g1_i + sum g1_src) + b1) ----------------
__global__ void k_agg1(const __bf16* __restrict__ g1, const int* __restrict__ csr,
                       const int* __restrict__ off, const int* __restrict__ cnt,
                       const float* __restrict__ dinv, const float* __restrict__ b1,
                       __bf16* __restrict__ z1, int n) {
    int node = blockIdx.x * 4 + (threadIdx.x >> 6);
    if (node >= n) return;
    int l = threadIdx.x & 63;
    const __bf16* base = g1 + (size_t)l * 4;
    bf16x4 v = *(const bf16x4*)(base + (size_t)node * HID);
    float a0 = (float)v[0], a1 = (float)v[1], a2 = (float)v[2], a3 = (float)v[3];
    float c0 = 0.f, c1 = 0.f, c2 = 0.f, c3 = 0.f;
    int e = off[node], e0 = e + cnt[node];
    for (; e + 3 < e0; e += 4) {                 // 4 loads in flight, 2 acc chains
        int sA = csr[e], sB = csr[e + 1], sC = csr[e + 2], sD = csr[e + 3];
        bf16x4 uA = *(const bf16x4*)(base + (size_t)sA * HID);
        bf16x4 uB = *(const bf16x4*)(base + (size_t)sB * HID);
        bf16x4 uC = *(const bf16x4*)(base + (size_t)sC * HID);
        bf16x4 uD = *(const bf16x4*)(base + (size_t)sD * HID);
        a0 += (float)uA[0] + (float)uC[0]; c0 += (float)uB[0] + (float)uD[0];
        a1 += (float)uA[1] + (float)uC[1]; c1 += (float)uB[1] + (float)uD[1];
        a2 += (float)uA[2] + (float)uC[2]; c2 += (float)uB[2] + (float)uD[2];
        a3 += (float)uA[3] + (float)uC[3]; c3 += (float)uB[3] + (float)uD[3];
    }
    for (; e < e0; ++e) {
        int s = csr[e];
        bf16x4 u = *(const bf16x4*)(base + (size_t)s * HID);
        a0 += (float)u[0]; a1 += (float)u[1]; a2 += (float)u[2]; a3 += (float)u[3];
    }
    float di = dinv[node];
    f32x4 b = *(const f32x4*)(b1 + l * 4);
    bf16x4 o;
    o[0] = (__bf16)fmaxf((a0 + c0) * di + b[0], 0.f);
    o[1] = (__bf16)fmaxf((a1 + c1) * di + b[1], 0.f);
    o[2] = (__bf16)fmaxf((a2 + c2) * di + b[2], 0.f);
    o[3] = (__bf16)fmaxf((a3 + c3) * di + b[3], 0.f);
    *(bf16x4*)(z1 + (size_t)node * HID + l * 4) = o;
}

// ---------------- aggregation 2: out = dinv_i*(g2_i + sum g2_src) + b2 (f32) ----------------
__global__ void k_agg2(const __bf16* __restrict__ g2, const int* __restrict__ csr,
                       const int* __restrict__ off, const int* __restrict__ cnt,
                       const float* __restrict__ dinv, const float* __restrict__ b2,
                       float* __restrict__ out, int n) {
    int node = blockIdx.x * 4 + (threadIdx.x >> 6);
    if (node >= n) return;
    int l = threadIdx.x & 63;
    const __bf16* base = g2 + (size_t)l * 2;
    bf16x2 v = *(const bf16x2*)(base + (size_t)node * DOUT);
    float a0 = (float)v[0], a1 = (float)v[1];
    float c0 = 0.f, c1 = 0.f;
    int e = off[node], e0 = e + cnt[node];
    for (; e + 3 < e0; e += 4) {
        int sA = csr[e], sB = csr[e + 1], sC = csr[e + 2], sD = csr[e + 3];
        bf16x2 uA = *(const bf16x2*)(base + (size_t)sA * DOUT);
        bf16x2 uB = *(const bf16x2*)(base + (size_t)sB * DOUT);
        bf16x2 uC = *(const bf16x2*)(base + (size_t)sC * DOUT);
        bf16x2 uD = *(const bf16x2*)(base + (size_t)sD * DOUT);
        a0 += (float)uA[0] + (float)uC[0]; c0 += (float)uB[0] + (float)uD[0];
        a1 += (float)uA[1] + (float)uC[1]; c1 += (float)uB[1] + (float)uD[1];
    }
    for (; e < e0; ++e) {
        int s = csr[e];
        bf16x2 u = *(const bf16x2*)(base + (size_t)s * DOUT);
        a0 += (float)u[0]; a1 += (float)u[1];
    }
    float di = dinv[node];
    f32x2 b = *(const f32x2*)(b2 + l * 2);
    f32x2 o;
    o[0] = (a0 + c0) * di + b[0];
    o[1] = (a1 + c1) * di + b[1];
    *(f32x2*)(out + (size_t)node * DOUT + l * 2) = o;
}

extern "C" void kernel_launch(void* const* d_in, const int* in_sizes, int n_in,
                              void* d_out, int out_size, void* d_ws, size_t ws_size,
                              hipStream_t stream) {
    const float* x  = (const float*)d_in[0];
    const int*   ei = (const int*)d_in[1];
    const float* W1 = (const float*)d_in[2];
    const float* b1 = (const float*)d_in[3];
    const float* W2 = (const float*)d_in[4];
    const float* b2 = (const float*)d_in[5];
    float* out = (float*)d_out;

    const int N = in_sizes[0] / FIN;
    const int E = in_sizes[1] / 2;
    const int* srcA = ei;
    const int* dstA = ei + E;

    uint8_t* w = (uint8_t*)d_ws;
    auto take = [&](size_t bytes) { uint8_t* p = w; w += (bytes + 255) & ~(size_t)255; return p; };
    int*    cnt  = (int*)take((size_t)N * 4);
    int*    cur  = (int*)take((size_t)N * 4);
    int*    off  = (int*)take((size_t)N * 4);
    float*  dinv = (float*)take((size_t)N * 4);
    int*    sums = (int*)take(4096);
    int*    csr  = (int*)take((size_t)E * 4);
    __bf16* W1t  = (__bf16*)take((size_t)FIN * HID * 2);
    __bf16* W2t  = (__bf16*)take((size_t)HID * DOUT * 2);
    __bf16* g1   = (__bf16*)take((size_t)N * HID * 2);
    __bf16* z1   = (__bf16*)take((size_t)N * HID * 2);
    __bf16* g2   = (__bf16*)take((size_t)N * DOUT * 2);

    hipMemsetAsync(cnt, 0, (size_t)N * 4, stream);
    hipMemsetAsync(cur, 0, (size_t)N * 4, stream);
    k_count<<<(E + 255) / 256, 256, 0, stream>>>(dstA, E, cnt);
    int nb = (N + 1023) / 1024;
    k_scan1<<<nb, 1024, 0, stream>>>(cnt, off, sums, N);
    k_scan2<<<1, 128, 0, stream>>>(sums, nb);
    k_scan_fix<<<(N + 255) / 256, 256, 0, stream>>>(off, sums, cnt, dinv, N);
    k_fill<<<(E + 255) / 256, 256, 0, stream>>>(srcA, dstA, E, off, cur, csr);

    k_prep_w<<<(FIN * HID + HID * DOUT + 255) / 256, 256, 0, stream>>>(W1, W2, W1t, W2t);

    const int gm = (N + 127) / 128;              // 782

    k_gemm1<<<gm, 256, 0, stream>>>(x, W1t, dinv, g1, N);
    k_agg1<<<(N + 3) / 4, 256, 0, stream>>>(g1, csr, off, cnt, dinv, b1, z1, N);
    k_gemm2<<<gm, 256, 0, stream>>>(z1, W2t, dinv, g2, N);
    k_agg2<<<(N + 3) / 4, 256, 0, stream>>>(g2, csr, off, cnt, dinv, b2, out, N);
}

// Round 4
// 547.426 us; speedup vs baseline: 1.1781x; 1.0320x over previous
//
#include <hip/hip_runtime.h>

// GCN 2-layer: out = Ahat * relu(Ahat*(x@W1)+b1) @ W2 + b2
// Ahat = D^-1/2 (A+I) D^-1/2.
// R4: aggs use one node per 32-lane group (2 nodes/wave, 2x MLP, exact row
// coverage: agg1 32x16B=512B, agg2 32x8B=256B), 8/4/1 unrolled gather loops.
// Fused memsets (adjacent carve) and count+prep_w (one launch).

typedef float   f32x4  __attribute__((ext_vector_type(4)));
typedef __bf16  bf16x8 __attribute__((ext_vector_type(8)));
typedef __bf16  bf16x4 __attribute__((ext_vector_type(4)));

#define FIN 512
#define HID 256
#define DOUT 128

__device__ __forceinline__ void gload16(const void* g, void* l) {
    __builtin_amdgcn_global_load_lds((const __attribute__((address_space(1))) void*)g,
                                     (__attribute__((address_space(3))) void*)l, 16, 0, 0);
}

// ---------------- CSR build + weight prep (fused independent work) ----------------
__global__ void k_count_prep(const int* __restrict__ dst, int E, int* __restrict__ cnt,
                             const float* __restrict__ W1, const float* __restrict__ W2,
                             __bf16* __restrict__ W1t, __bf16* __restrict__ W2t,
                             int nCountBlk) {
    if (blockIdx.x < nCountBlk) {
        int e = blockIdx.x * 256 + threadIdx.x;
        if (e < E) atomicAdd(&cnt[dst[e]], 1);
    } else {
        int id = (blockIdx.x - nCountBlk) * 256 + threadIdx.x;
        if (id < FIN * HID) {
            int k = id >> 8, n = id & 255;
            W1t[n * FIN + k] = (__bf16)W1[id];
        }
        int id2 = id - FIN * HID;
        if (id2 >= 0 && id2 < HID * DOUT) {
            int k = id2 >> 7, n = id2 & 127;
            W2t[n * HID + k] = (__bf16)W2[id2];
        }
    }
}

__global__ void k_scan1(const int* __restrict__ cnt, int* __restrict__ off,
                        int* __restrict__ sums, int n) {
    __shared__ int s[1024];
    int i = blockIdx.x * 1024 + threadIdx.x;
    int v = (i < n) ? cnt[i] : 0;
    s[threadIdx.x] = v;
    __syncthreads();
    for (int d = 1; d < 1024; d <<= 1) {
        int t = (threadIdx.x >= d) ? s[threadIdx.x - d] : 0;
        __syncthreads();
        s[threadIdx.x] += t;
        __syncthreads();
    }
    if (i < n) off[i] = s[threadIdx.x] - v;
    if (threadIdx.x == 1023) sums[blockIdx.x] = s[1023];
}

__global__ void k_scan2(int* __restrict__ sums, int nb) {
    __shared__ int s[128];
    int t = threadIdx.x;
    int v = (t < nb) ? sums[t] : 0;
    s[t] = v;
    __syncthreads();
    for (int d = 1; d < 128; d <<= 1) {
        int u = (t >= d) ? s[t - d] : 0;
        __syncthreads();
        s[t] += u;
        __syncthreads();
    }
    if (t < nb) sums[t] = s[t] - v;
}

__global__ void k_scan_fix(int* __restrict__ off, const int* __restrict__ sums,
                           const int* __restrict__ cnt, float* __restrict__ dinv, int n) {
    int i = blockIdx.x * 256 + threadIdx.x;
    if (i < n) {
        off[i] += sums[i >> 10];
        dinv[i] = rsqrtf((float)(cnt[i] + 1));
    }
}

__global__ void k_fill(const int* __restrict__ src, const int* __restrict__ dst, int E,
                       const int* __restrict__ off, int* __restrict__ cur,
                       int* __restrict__ csr) {
    int e = blockIdx.x * 256 + threadIdx.x;
    if (e < E) {
        int d = dst[e];
        int p = atomicAdd(&cur[d], 1);
        csr[off[d] + p] = src[e];
    }
}

// ---------------- GEMM1: g1 = bf16(dinv * (x @ W1)), x f32 [M][512], out [M][256] ----------------
__global__ __launch_bounds__(256, 2) void k_gemm1(
    const float* __restrict__ x, const __bf16* __restrict__ Bt,
    const float* __restrict__ dinv, __bf16* __restrict__ g1, int M) {
    __shared__ __bf16 Albuf[2][128 * 32];
    __shared__ __bf16 Blbuf[2][256 * 32];

    const int tid = threadIdx.x;
    const int l = tid & 63, wid = tid >> 6;
    const int wm = wid & 1, wn = wid >> 1;
    const int r15 = l & 15, hi = l >> 4;
    const long bm = blockIdx.x;

    const int arow = tid >> 1, aseg = tid & 1;
    long ag = bm * 128 + arow;
    if (ag >= M) ag = M - 1;
    const float* aptr = x + ag * (long)FIN + aseg * 16;
    const int aoff = arow * 32 + aseg * 16;

    const int bo0 = wid * 4096;

    f32x4 acc[4][8] = {};

    auto stageB = [&](int kb, int buf) {
#pragma unroll
        for (int i = 0; i < 4; ++i) {
            int ob = bo0 + i * 1024;
            int o = ob + l * 16;
            int n = o >> 6, cb = o & 63;
            const char* src = (const char*)Bt + (long)n * (FIN * 2) + kb * 64 + cb;
            gload16(src, (char*)&Blbuf[buf][0] + ob);
        }
    };

    stageB(0, 0);
    {
        const f32x4* p = (const f32x4*)aptr;
        f32x4 p0 = p[0], p1 = p[1], p2 = p[2], p3 = p[3];
        bf16x8 w0, w1;
#pragma unroll
        for (int j = 0; j < 4; ++j) {
            w0[j] = (__bf16)p0[j]; w0[j + 4] = (__bf16)p1[j];
            w1[j] = (__bf16)p2[j]; w1[j + 4] = (__bf16)p3[j];
        }
        *(bf16x8*)&Albuf[0][aoff] = w0;
        *(bf16x8*)&Albuf[0][aoff + 8] = w1;
    }
    __syncthreads();

    int cur = 0;
    constexpr int NT = FIN / 32;
    for (int kb = 0; kb < NT; ++kb) {
        const int nxt = cur ^ 1;
        const bool pf = (kb + 1 < NT);
        f32x4 p0, p1, p2, p3;
        if (pf) {
            stageB(kb + 1, nxt);
            const f32x4* p = (const f32x4*)(aptr + (kb + 1) * 32);
            p0 = p[0]; p1 = p[1]; p2 = p[2]; p3 = p[3];
        }

        bf16x8 af[4], bfr[8];
#pragma unroll
        for (int m = 0; m < 4; ++m)
            af[m] = *(const bf16x8*)&Albuf[cur][(wm * 64 + m * 16 + r15) * 32 + hi * 8];
#pragma unroll
        for (int n = 0; n < 8; ++n)
            bfr[n] = *(const bf16x8*)&Blbuf[cur][(wn * 128 + n * 16 + r15) * 32 + hi * 8];
#pragma unroll
        for (int m = 0; m < 4; ++m)
#pragma unroll
            for (int n = 0; n < 8; ++n)
                acc[m][n] = __builtin_amdgcn_mfma_f32_16x16x32_bf16(bfr[n], af[m], acc[m][n], 0, 0, 0);

        if (pf) {
            bf16x8 w0, w1;
#pragma unroll
            for (int j = 0; j < 4; ++j) {
                w0[j] = (__bf16)p0[j]; w0[j + 4] = (__bf16)p1[j];
                w1[j] = (__bf16)p2[j]; w1[j + 4] = (__bf16)p3[j];
            }
            *(bf16x8*)&Albuf[nxt][aoff] = w0;
            *(bf16x8*)&Albuf[nxt][aoff + 8] = w1;
        }
        __syncthreads();
        cur = nxt;
    }

#pragma unroll
    for (int m = 0; m < 4; ++m) {
        long rg = bm * 128 + wm * 64 + m * 16 + r15;
        if (rg >= M) continue;
        float di = dinv[rg];
#pragma unroll
        for (int n = 0; n < 8; ++n) {
            bf16x4 o;
            o[0] = (__bf16)(acc[m][n][0] * di);
            o[1] = (__bf16)(acc[m][n][1] * di);
            o[2] = (__bf16)(acc[m][n][2] * di);
            o[3] = (__bf16)(acc[m][n][3] * di);
            int c = wn * 128 + n * 16 + hi * 4;
            *(bf16x4*)(g1 + rg * (long)HID + c) = o;
        }
    }
}

// ---------------- GEMM2: g2 = bf16(dinv * (z1 @ W2)) ----------------
__global__ __launch_bounds__(256, 3) void k_gemm2(
    const __bf16* __restrict__ z1, const __bf16* __restrict__ Bt,
    const float* __restrict__ dinv, __bf16* __restrict__ g2, int M) {
    __shared__ __bf16 Albuf[2][128 * 32];
    __shared__ __bf16 Blbuf[2][128 * 32];

    const int tid = threadIdx.x;
    const int l = tid & 63, wid = tid >> 6;
    const int wm = wid & 1, wn = wid >> 1;
    const int r15 = l & 15, hi = l >> 4;
    const long bm = blockIdx.x;

    f32x4 acc[4][4] = {};

    auto stage = [&](int kb, int buf) {
#pragma unroll
        for (int i = 0; i < 2; ++i) {
            int ob = wid * 2048 + i * 1024;
            int o = ob + l * 16;
            long r = bm * 128 + (o >> 6);
            if (r >= M) r = M - 1;
            const char* src = (const char*)z1 + r * (HID * 2) + kb * 64 + (o & 63);
            gload16(src, (char*)&Albuf[buf][0] + ob);
        }
#pragma unroll
        for (int i = 0; i < 2; ++i) {
            int ob = wid * 2048 + i * 1024;
            int o = ob + l * 16;
            int n = o >> 6;
            const char* src = (const char*)Bt + (long)n * (HID * 2) + kb * 64 + (o & 63);
            gload16(src, (char*)&Blbuf[buf][0] + ob);
        }
    };

    stage(0, 0);
    __syncthreads();

    int cur = 0;
    constexpr int NT = HID / 32;
    for (int kb = 0; kb < NT; ++kb) {
        const int nxt = cur ^ 1;
        if (kb + 1 < NT) stage(kb + 1, nxt);

        bf16x8 af[4], bfr[4];
#pragma unroll
        for (int m = 0; m < 4; ++m)
            af[m] = *(const bf16x8*)&Albuf[cur][(wm * 64 + m * 16 + r15) * 32 + hi * 8];
#pragma unroll
        for (int n = 0; n < 4; ++n)
            bfr[n] = *(const bf16x8*)&Blbuf[cur][(wn * 64 + n * 16 + r15) * 32 + hi * 8];
#pragma unroll
        for (int m = 0; m < 4; ++m)
#pragma unroll
            for (int n = 0; n < 4; ++n)
                acc[m][n] = __builtin_amdgcn_mfma_f32_16x16x32_bf16(bfr[n], af[m], acc[m][n], 0, 0, 0);

        __syncthreads();
        cur = nxt;
    }

#pragma unroll
    for (int m = 0; m < 4; ++m) {
        long rg = bm * 128 + wm * 64 + m * 16 + r15;
        if (rg >= M) continue;
        float di = dinv[rg];
#pragma unroll
        for (int n = 0; n < 4; ++n) {
            bf16x4 o;
            o[0] = (__bf16)(acc[m][n][0] * di);
            o[1] = (__bf16)(acc[m][n][1] * di);
            o[2] = (__bf16)(acc[m][n][2] * di);
            o[3] = (__bf16)(acc[m][n][3] * di);
            int c = wn * 64 + n * 16 + hi * 4;
            *(bf16x4*)(g2 + rg * (long)DOUT + c) = o;
        }
    }
}

// ---------------- agg1: one node per 32-lane group, lane = 16B (bf16x8) of the 512B row ----------------
__global__ void k_agg1(const __bf16* __restrict__ g1, const int* __restrict__ csr,
                       const int* __restrict__ off, const int* __restrict__ cnt,
                       const float* __restrict__ dinv, const float* __restrict__ b1,
                       __bf16* __restrict__ z1, int n) {
    int node = blockIdx.x * 8 + (threadIdx.x >> 5);
    if (node >= n) return;
    int l = threadIdx.x & 31;                    // feats 8l..8l+7
    const __bf16* base = g1 + (size_t)l * 8;
    float a[8], c[8];
    {
        bf16x8 v = *(const bf16x8*)(base + (size_t)node * HID);
#pragma unroll
        for (int j = 0; j < 8; ++j) { a[j] = (float)v[j]; c[j] = 0.f; }
    }
    int e = off[node], e0 = e + cnt[node];
    for (; e + 7 < e0; e += 8) {                 // 8 gathers in flight per group
        int s0 = csr[e], s1 = csr[e + 1], s2 = csr[e + 2], s3 = csr[e + 3];
        int s4 = csr[e + 4], s5 = csr[e + 5], s6 = csr[e + 6], s7 = csr[e + 7];
        bf16x8 u0 = *(const bf16x8*)(base + (size_t)s0 * HID);
        bf16x8 u1 = *(const bf16x8*)(base + (size_t)s1 * HID);
        bf16x8 u2 = *(const bf16x8*)(base + (size_t)s2 * HID);
        bf16x8 u3 = *(const bf16x8*)(base + (size_t)s3 * HID);
        bf16x8 u4 = *(const bf16x8*)(base + (size_t)s4 * HID);
        bf16x8 u5 = *(const bf16x8*)(base + (size_t)s5 * HID);
        bf16x8 u6 = *(const bf16x8*)(base + (size_t)s6 * HID);
        bf16x8 u7 = *(const bf16x8*)(base + (size_t)s7 * HID);
#pragma unroll
        for (int j = 0; j < 8; ++j) {
            a[j] += (float)u0[j] + (float)u2[j] + (float)u4[j] + (float)u6[j];
            c[j] += (float)u1[j] + (float)u3[j] + (float)u5[j] + (float)u7[j];
        }
    }
    for (; e + 3 < e0; e += 4) {
        int s0 = csr[e], s1 = csr[e + 1], s2 = csr[e + 2], s3 = csr[e + 3];
        bf16x8 u0 = *(const bf16x8*)(base + (size_t)s0 * HID);
        bf16x8 u1 = *(const bf16x8*)(base + (size_t)s1 * HID);
        bf16x8 u2 = *(const bf16x8*)(base + (size_t)s2 * HID);
        bf16x8 u3 = *(const bf16x8*)(base + (size_t)s3 * HID);
#pragma unroll
        for (int j = 0; j < 8; ++j) {
            a[j] += (float)u0[j] + (float)u2[j];
            c[j] += (float)u1[j] + (float)u3[j];
        }
    }
    for (; e < e0; ++e) {
        int s = csr[e];
        bf16x8 u = *(const bf16x8*)(base + (size_t)s * HID);
#pragma unroll
        for (int j = 0; j < 8; ++j) a[j] += (float)u[j];
    }
    float di = dinv[node];
    f32x4 bA = *(const f32x4*)(b1 + l * 8);
    f32x4 bB = *(const f32x4*)(b1 + l * 8 + 4);
    bf16x8 o;
#pragma unroll
    for (int j = 0; j < 4; ++j) {
        o[j]     = (__bf16)fmaxf((a[j] + c[j]) * di + bA[j], 0.f);
        o[j + 4] = (__bf16)fmaxf((a[j + 4] + c[j + 4]) * di + bB[j], 0.f);
    }
    *(bf16x8*)(z1 + (size_t)node * HID + l * 8) = o;
}

// ---------------- agg2: one node per 32-lane group, lane = 8B (bf16x4) of the 256B row ----------------
__global__ void k_agg2(const __bf16* __restrict__ g2, const int* __restrict__ csr,
                       const int* __restrict__ off, const int* __restrict__ cnt,
                       const float* __restrict__ dinv, const float* __restrict__ b2,
                       float* __restrict__ out, int n) {
    int node = blockIdx.x * 8 + (threadIdx.x >> 5);
    if (node >= n) return;
    int l = threadIdx.x & 31;                    // feats 4l..4l+3
    const __bf16* base = g2 + (size_t)l * 4;
    float a[4], c[4];
    {
        bf16x4 v = *(const bf16x4*)(base + (size_t)node * DOUT);
#pragma unroll
        for (int j = 0; j < 4; ++j) { a[j] = (float)v[j]; c[j] = 0.f; }
    }
    int e = off[node], e0 = e + cnt[node];
    for (; e + 7 < e0; e += 8) {
        int s0 = csr[e], s1 = csr[e + 1], s2 = csr[e + 2], s3 = csr[e + 3];
        int s4 = csr[e + 4], s5 = csr[e + 5], s6 = csr[e + 6], s7 = csr[e + 7];
        bf16x4 u0 = *(const bf16x4*)(base + (size_t)s0 * DOUT);
        bf16x4 u1 = *(const bf16x4*)(base + (size_t)s1 * DOUT);
        bf16x4 u2 = *(const bf16x4*)(base + (size_t)s2 * DOUT);
        bf16x4 u3 = *(const bf16x4*)(base + (size_t)s3 * DOUT);
        bf16x4 u4 = *(const bf16x4*)(base + (size_t)s4 * DOUT);
        bf16x4 u5 = *(const bf16x4*)(base + (size_t)s5 * DOUT);
        bf16x4 u6 = *(const bf16x4*)(base + (size_t)s6 * DOUT);
        bf16x4 u7 = *(const bf16x4*)(base + (size_t)s7 * DOUT);
#pragma unroll
        for (int j = 0; j < 4; ++j) {
            a[j] += (float)u0[j] + (float)u2[j] + (float)u4[j] + (float)u6[j];
            c[j] += (float)u1[j] + (float)u3[j] + (float)u5[j] + (float)u7[j];
        }
    }
    for (; e + 3 < e0; e += 4) {
        int s0 = csr[e], s1 = csr[e + 1], s2 = csr[e + 2], s3 = csr[e + 3];
        bf16x4 u0 = *(const bf16x4*)(base + (size_t)s0 * DOUT);
        bf16x4 u1 = *(const bf16x4*)(base + (size_t)s1 * DOUT);
        bf16x4 u2 = *(const bf16x4*)(base + (size_t)s2 * DOUT);
        bf16x4 u3 = *(const bf16x4*)(base + (size_t)s3 * DOUT);
#pragma unroll
        for (int j = 0; j < 4; ++j) {
            a[j] += (float)u0[j] + (float)u2[j];
            c[j] += (float)u1[j] + (float)u3[j];
        }
    }
    for (; e < e0; ++e) {
        int s = csr[e];
        bf16x4 u = *(const bf16x4*)(base + (size_t)s * DOUT);
#pragma unroll
        for (int j = 0; j < 4; ++j) a[j] += (float)u[j];
    }
    float di = dinv[node];
    f32x4 b = *(const f32x4*)(b2 + l * 4);
    f32x4 o;
#pragma unroll
    for (int j = 0; j < 4; ++j) o[j] = (a[j] + c[j]) * di + b[j];
    *(f32x4*)(out + (size_t)node * DOUT + l * 4) = o;
}

extern "C" void kernel_launch(void* const* d_in, const int* in_sizes, int n_in,
                              void* d_out, int out_size, void* d_ws, size_t ws_size,
                              hipStream_t stream) {
    const float* x  = (const float*)d_in[0];
    const int*   ei = (const int*)d_in[1];
    const float* W1 = (const float*)d_in[2];
    const float* b1 = (const float*)d_in[3];
    const float* W2 = (const float*)d_in[4];
    const float* b2 = (const float*)d_in[5];
    float* out = (float*)d_out;

    const int N = in_sizes[0] / FIN;
    const int E = in_sizes[1] / 2;
    const int* srcA = ei;
    const int* dstA = ei + E;

    uint8_t* w = (uint8_t*)d_ws;
    auto take = [&](size_t bytes) { uint8_t* p = w; w += (bytes + 255) & ~(size_t)255; return p; };
    int*    cnt  = (int*)take((size_t)N * 4);    // cnt and cur adjacent: one memset
    int*    cur  = (int*)take((size_t)N * 4);
    int*    off  = (int*)take((size_t)N * 4);
    float*  dinv = (float*)take((size_t)N * 4);
    int*    sums = (int*)take(4096);
    int*    csr  = (int*)take((size_t)E * 4);
    __bf16* W1t  = (__bf16*)take((size_t)FIN * HID * 2);
    __bf16* W2t  = (__bf16*)take((size_t)HID * DOUT * 2);
    __bf16* g1   = (__bf16*)take((size_t)N * HID * 2);
    __bf16* z1   = (__bf16*)take((size_t)N * HID * 2);
    __bf16* g2   = (__bf16*)take((size_t)N * DOUT * 2);

    // one memset covers cnt + cur (adjacent carves)
    hipMemsetAsync(cnt, 0, (size_t)((uint8_t*)off - (uint8_t*)cnt), stream);

    const int nCountBlk = (E + 255) / 256;
    const int nPrepBlk = (FIN * HID + HID * DOUT + 255) / 256;
    k_count_prep<<<nCountBlk + nPrepBlk, 256, 0, stream>>>(dstA, E, cnt, W1, W2, W1t, W2t, nCountBlk);

    int nb = (N + 1023) / 1024;
    k_scan1<<<nb, 1024, 0, stream>>>(cnt, off, sums, N);
    k_scan2<<<1, 128, 0, stream>>>(sums, nb);
    k_scan_fix<<<(N + 255) / 256, 256, 0, stream>>>(off, sums, cnt, dinv, N);
    k_fill<<<(E + 255) / 256, 256, 0, stream>>>(srcA, dstA, E, off, cur, csr);

    const int gm = (N + 127) / 128;

    k_gemm1<<<gm, 256, 0, stream>>>(x, W1t, dinv, g1, N);
    k_agg1<<<(N + 7) / 8, 256, 0, stream>>>(g1, csr, off, cnt, dinv, b1, z1, N);
    k_gemm2<<<gm, 256, 0, stream>>>(z1, W2t, dinv, g2, N);
    k_agg2<<<(N + 7) / 8, 256, 0, stream>>>(g2, csr, off, cnt, dinv, b2, out, N);
}